// Round 14
// baseline (63.934 us; speedup 1.0000x reference)
//
#include <hip/hip_runtime.h>

#define R_    116
#define DIN_  116
#define H_    256

typedef float  f32x4   __attribute__((ext_vector_type(4)));
typedef float  f32x16  __attribute__((ext_vector_type(16)));
typedef short  short8  __attribute__((ext_vector_type(8)));
typedef int    int4v   __attribute__((ext_vector_type(4)));
typedef int    int2v   __attribute__((ext_vector_type(2)));

// ---- LDS layout (bytes). 16B-block XOR swizzle per row (block ^= row&7).
#define M_OFF    0        // M  [128 c][128 r] bf16 pitch 256B : bb=(r>>3)^(c&7); relu(m^T)+I
#define X_OFF    32768    // X  [128 r][128 k] bf16 pitch 256B : bb=(k>>3)^(r&7); zero-padded
#define H1_OFF   65536    // H1 [128 c][256 f] bf16 pitch 512B : bb=(f>>3)^(c&7); rows>=116 zeroed
#define DINV_OFF 131072   // 128 f32 (persistent)
#define RED_OFF  131584   // 16 f32
#define LDS_SIZE 131712

#define Z16 {0.f,0.f,0.f,0.f,0.f,0.f,0.f,0.f,0.f,0.f,0.f,0.f,0.f,0.f,0.f,0.f}

__device__ __forceinline__ short f2bf(float f) {
  union { float f; unsigned u; } x; x.f = f;
  unsigned r = x.u + 0x7fffu + ((x.u >> 16) & 1u);
  return (short)(r >> 16);
}
__device__ __forceinline__ float bf2f(short s) {
  union { unsigned u; float f; } x;
  x.u = ((unsigned)(unsigned short)s) << 16;
  return x.f;
}
__device__ __forceinline__ unsigned pack2(float lo, float hi) {
  return (unsigned)(unsigned short)f2bf(lo) | ((unsigned)(unsigned short)f2bf(hi) << 16);
}
__device__ __forceinline__ short8 mk8(unsigned a, unsigned b, unsigned c, unsigned d) {
  int4v t; t[0] = (int)a; t[1] = (int)b; t[2] = (int)c; t[3] = (int)d;
  return __builtin_bit_cast(short8, t);
}

// Pre-transpose weights to bf16 Wt[f][k], zero-padded K (layer 1).
__global__ void __launch_bounds__(256) wt_setup(const float* __restrict__ W1,
                                                const float* __restrict__ W2,
                                                short* __restrict__ W1t,
                                                short* __restrict__ W2t) {
  int idx = blockIdx.x * 256 + threadIdx.x;      // 384 blocks
  if (idx < 32768) {                             // W1t [256][128]
    int f = idx >> 7, k = idx & 127;
    float v = (k < DIN_) ? W1[k * H_ + f] : 0.f;
    W1t[idx] = f2bf(v);
  } else {                                       // W2t [256][256]
    int j = idx - 32768;
    int f = j >> 8, k = j & 255;
    W2t[j] = f2bf(W2[k * H_ + f]);
  }
}

// 8 waves (512 thr), 32x32x16 MFMA. Wave w owns f-tile w*32..w*32+31 for BOTH layers.
// Phase A: D[r-quads][f=n32] = X @ W.  In-register transform (scale by dinv[r],
// pack to bf16, shfl_xor lane^32) builds phase-B A-frags xs[f=n32][r-slice]
// WITHOUT an LDS round-trip or barrier.  Phase B: D2[f-quads][c=n32] += xs @ M^T.
__global__ void __launch_bounds__(512, 2) gnn_fused(
    const float* __restrict__ mM, const float* __restrict__ nf,
    const float* __restrict__ b1, const float* __restrict__ b2,
    const float* __restrict__ Wc, const float* __restrict__ bc,
    const short* __restrict__ W1t, const short* __restrict__ W2t,
    float* __restrict__ out)
{
  extern __shared__ char smem[];
  const int b    = blockIdx.x;
  const int tid  = threadIdx.x;
  const int lane = tid & 63;
  const int w    = tid >> 6;     // 0..7 : f-tile (32 cols, both layers)
  const int n32  = lane & 31;
  const int hi   = lane >> 5;
  const int s7   = n32 & 7;

  // ---- W1 fragments: pure global loads (no LDS dependency) issued first so
  //      their latency hides under the whole prologue.  Same values as r12. ----
  short8 w1f[8];
#pragma unroll
  for (int ks = 0; ks < 8; ++ks)
    w1f[ks] = *(const short8*)(W1t + (size_t)(w * 32 + n32) * 128 + ks * 16 + hi * 8);

  // ---- zero M + X + H1 (128KB: covers all padding incl. H1 rows >= 116) ----
  for (int t = tid; t < 131072 / 16; t += 512)
    ((int4v*)smem)[t] = (int4v){0, 0, 0, 0};
  __syncthreads();

  // ---- fill M (transposed, relu, +1 diag) and X (bf16), coalesced f32x4 reads ----
  {
    const float* mB = mM + (size_t)b * (R_ * R_);
    const float* xB = nf + (size_t)b * (R_ * DIN_);
    for (int t4 = tid; t4 < (R_ * R_) / 4; t4 += 512) {
      f32x4 v4 = ((const f32x4*)mB)[t4];
      f32x4 x4 = ((const f32x4*)xB)[t4];
      int i0 = t4 * 4;
      int r = i0 / R_, c0 = i0 - r * R_;          // c0 % 4 == 0 (116 % 4 == 0)
#pragma unroll
      for (int e = 0; e < 4; ++e) {               // M: rows differ -> scalar stores
        int c = c0 + e;
        float v = v4[e];
        v = v > 0.f ? v : 0.f;
        if (r == c) v += 1.f;
        int ba = (r >> 3) ^ (c & 7);
        *(short*)(smem + M_OFF + c * 256 + ba * 16 + (r & 7) * 2) = f2bf(v);
      }
      {                                           // X: same row -> one 8B store
        int bx = (c0 >> 3) ^ (r & 7);
        int2v px;
        px[0] = (int)pack2(x4[0], x4[1]);
        px[1] = (int)pack2(x4[2], x4[3]);
        *(int2v*)(smem + X_OFF + r * 256 + bx * 16 + (c0 & 7) * 2) = px;
      }
    }
  }
  __syncthreads();

  // ---- deg/dinv: 4 threads per row -> persistent DINV region ----
  {
    float* dp = (float*)(smem + DINV_OFF);
    int row = tid >> 2, part = tid & 3;
    float s = 0.f;
#pragma unroll
    for (int j = 0; j < 4; ++j) {
      int bb = (part * 4 + j) ^ (row & 7);
      short8 v = *(const short8*)(smem + M_OFF + row * 256 + bb * 16);
#pragma unroll
      for (int e = 0; e < 8; ++e) s += bf2f(v[e]);
    }
    s += __shfl_xor(s, 1);
    s += __shfl_xor(s, 2);
    if (part == 0) dp[row] = (row < R_) ? rsqrtf(s) : 0.f;
  }
  __syncthreads();

  const float* dinvp = (const float*)(smem + DINV_OFF);
  float dvc[4];
#pragma unroll
  for (int ct = 0; ct < 4; ++ct) dvc[ct] = dinvp[ct * 32 + n32];

  float ps0 = 0.f, ps1 = 0.f;

  // ================= Layer 1 (no internal barriers) =================
  {
    f32x16 acc2[4];
#pragma unroll
    for (int ct = 0; ct < 4; ++ct) acc2[ct] = (f32x16)Z16;

#pragma unroll
    for (int rb = 0; rb < 4; ++rb) {
      // phase A: xw tile [32 r x 32 f], split accumulator (2x ILP on the chain)
      f32x16 accA = (f32x16)Z16, accB = (f32x16)Z16;
#pragma unroll
      for (int ks = 0; ks < 4; ++ks) {
        short8 xa0 = *(const short8*)(smem + X_OFF + (rb * 32 + n32) * 256 +
                                      (((ks * 2 + hi) ^ s7)) * 16);
        accA = __builtin_amdgcn_mfma_f32_32x32x16_bf16(xa0, w1f[ks], accA, 0, 0, 0);
        short8 xa1 = *(const short8*)(smem + X_OFF + (rb * 32 + n32) * 256 +
                                      ((((ks + 4) * 2 + hi) ^ s7)) * 16);
        accB = __builtin_amdgcn_mfma_f32_32x32x16_bf16(xa1, w1f[ks + 4], accB, 0, 0, 0);
      }
      f32x16 acc = accA + accB;
      // in-register: scale by dinv[r], pack bf16, exchange lane^32 -> A-frags
      f32x4 dv0 = *(const f32x4*)(dinvp + rb * 32 + 0 + hi * 4);
      f32x4 dv1 = *(const f32x4*)(dinvp + rb * 32 + 8 + hi * 4);
      f32x4 dv2 = *(const f32x4*)(dinvp + rb * 32 + 16 + hi * 4);
      f32x4 dv3 = *(const f32x4*)(dinvp + rb * 32 + 24 + hi * 4);
      unsigned pk0l = pack2(acc[0] * dv0[0],  acc[1] * dv0[1]);
      unsigned pk0h = pack2(acc[2] * dv0[2],  acc[3] * dv0[3]);
      unsigned pk1l = pack2(acc[4] * dv1[0],  acc[5] * dv1[1]);
      unsigned pk1h = pack2(acc[6] * dv1[2],  acc[7] * dv1[3]);
      unsigned pk2l = pack2(acc[8] * dv2[0],  acc[9] * dv2[1]);
      unsigned pk2h = pack2(acc[10] * dv2[2], acc[11] * dv2[3]);
      unsigned pk3l = pack2(acc[12] * dv3[0], acc[13] * dv3[1]);
      unsigned pk3h = pack2(acc[14] * dv3[2], acc[15] * dv3[3]);
      unsigned rv0l = (unsigned)__shfl_xor((int)pk0l, 32);
      unsigned rv0h = (unsigned)__shfl_xor((int)pk0h, 32);
      unsigned rv1l = (unsigned)__shfl_xor((int)pk1l, 32);
      unsigned rv1h = (unsigned)__shfl_xor((int)pk1h, 32);
      unsigned rv2l = (unsigned)__shfl_xor((int)pk2l, 32);
      unsigned rv2h = (unsigned)__shfl_xor((int)pk2h, 32);
      unsigned rv3l = (unsigned)__shfl_xor((int)pk3l, 32);
      unsigned rv3h = (unsigned)__shfl_xor((int)pk3h, 32);
      short8 A0 = mk8(hi ? rv1l : pk0l, hi ? rv1h : pk0h,
                      hi ? pk1l : rv0l, hi ? pk1h : rv0h);
      short8 A1 = mk8(hi ? rv3l : pk2l, hi ? rv3h : pk2h,
                      hi ? pk3l : rv2l, hi ? pk3h : rv2h);
      // phase B: D2[f-quads][c=n32] += xs @ M^T (K = this rb's 32 r)
#pragma unroll
      for (int ct = 0; ct < 4; ++ct) {
        int c = ct * 32 + n32;
        short8 B0 = *(const short8*)(smem + M_OFF + c * 256 + ((rb * 4 + hi) ^ s7) * 16);
        short8 B1 = *(const short8*)(smem + M_OFF + c * 256 + ((rb * 4 + 2 + hi) ^ s7) * 16);
        acc2[ct] = __builtin_amdgcn_mfma_f32_32x32x16_bf16(A0, B0, acc2[ct], 0, 0, 0);
        acc2[ct] = __builtin_amdgcn_mfma_f32_32x32x16_bf16(A1, B1, acc2[ct], 0, 0, 0);
      }
    }

    // epilogue: h1 = leaky(dinv[c]*agg + b1[f]) -> H1[c][f]
    f32x4 bv[4];
#pragma unroll
    for (int rq = 0; rq < 4; ++rq)
      bv[rq] = *(const f32x4*)(b1 + w * 32 + rq * 8 + hi * 4);
#pragma unroll
    for (int ct = 0; ct < 4; ++ct) {
      int c = ct * 32 + n32;
      if (c < R_) {
        float dv = dvc[ct];
#pragma unroll
        for (int rq = 0; rq < 4; ++rq) {
          const int f0 = w * 32 + rq * 8 + hi * 4;
          float h0 = dv * acc2[ct][rq * 4 + 0] + bv[rq][0]; h0 = h0 > 0.f ? h0 : 0.2f * h0;
          float h1 = dv * acc2[ct][rq * 4 + 1] + bv[rq][1]; h1 = h1 > 0.f ? h1 : 0.2f * h1;
          float h2 = dv * acc2[ct][rq * 4 + 2] + bv[rq][2]; h2 = h2 > 0.f ? h2 : 0.2f * h2;
          float h3 = dv * acc2[ct][rq * 4 + 3] + bv[rq][3]; h3 = h3 > 0.f ? h3 : 0.2f * h3;
          int bb = (w * 4 + rq) ^ s7;            // (f0>>3)^(c&7), c&7==s7
          int2v pk;
          pk[0] = (int)pack2(h0, h1);
          pk[1] = (int)pack2(h2, h3);
          *(int2v*)(smem + H1_OFF + c * 512 + bb * 16 + hi * 8) = pk;
        }
      }
    }
  }
  __syncthreads();   // H1 complete

  // ================= Layer 2 (no internal barriers) =================
  {
    f32x16 acc2[4];
#pragma unroll
    for (int ct = 0; ct < 4; ++ct) acc2[ct] = (f32x16)Z16;

#pragma unroll
    for (int rb = 0; rb < 4; ++rb) {
      // phase A: split accumulator (2x ILP on the 16-deep chain)
      f32x16 accA = (f32x16)Z16, accB = (f32x16)Z16;
#pragma unroll
      for (int ks = 0; ks < 8; ++ks) {
        short8 ha0 = *(const short8*)(smem + H1_OFF + (rb * 32 + n32) * 512 +
                                      (((ks * 2 + hi) ^ s7)) * 16);
        short8 wf0 = *(const short8*)(W2t + (size_t)(w * 32 + n32) * 256 + ks * 16 + hi * 8);
        accA = __builtin_amdgcn_mfma_f32_32x32x16_bf16(ha0, wf0, accA, 0, 0, 0);
        short8 ha1 = *(const short8*)(smem + H1_OFF + (rb * 32 + n32) * 512 +
                                      ((((ks + 8) * 2 + hi) ^ s7)) * 16);
        short8 wf1 = *(const short8*)(W2t + (size_t)(w * 32 + n32) * 256 + (ks + 8) * 16 + hi * 8);
        accB = __builtin_amdgcn_mfma_f32_32x32x16_bf16(ha1, wf1, accB, 0, 0, 0);
      }
      f32x16 acc = accA + accB;
      f32x4 dv0 = *(const f32x4*)(dinvp + rb * 32 + 0 + hi * 4);
      f32x4 dv1 = *(const f32x4*)(dinvp + rb * 32 + 8 + hi * 4);
      f32x4 dv2 = *(const f32x4*)(dinvp + rb * 32 + 16 + hi * 4);
      f32x4 dv3 = *(const f32x4*)(dinvp + rb * 32 + 24 + hi * 4);
      unsigned pk0l = pack2(acc[0] * dv0[0],  acc[1] * dv0[1]);
      unsigned pk0h = pack2(acc[2] * dv0[2],  acc[3] * dv0[3]);
      unsigned pk1l = pack2(acc[4] * dv1[0],  acc[5] * dv1[1]);
      unsigned pk1h = pack2(acc[6] * dv1[2],  acc[7] * dv1[3]);
      unsigned pk2l = pack2(acc[8] * dv2[0],  acc[9] * dv2[1]);
      unsigned pk2h = pack2(acc[10] * dv2[2], acc[11] * dv2[3]);
      unsigned pk3l = pack2(acc[12] * dv3[0], acc[13] * dv3[1]);
      unsigned pk3h = pack2(acc[14] * dv3[2], acc[15] * dv3[3]);
      unsigned rv0l = (unsigned)__shfl_xor((int)pk0l, 32);
      unsigned rv0h = (unsigned)__shfl_xor((int)pk0h, 32);
      unsigned rv1l = (unsigned)__shfl_xor((int)pk1l, 32);
      unsigned rv1h = (unsigned)__shfl_xor((int)pk1h, 32);
      unsigned rv2l = (unsigned)__shfl_xor((int)pk2l, 32);
      unsigned rv2h = (unsigned)__shfl_xor((int)pk2h, 32);
      unsigned rv3l = (unsigned)__shfl_xor((int)pk3l, 32);
      unsigned rv3h = (unsigned)__shfl_xor((int)pk3h, 32);
      short8 A0 = mk8(hi ? rv1l : pk0l, hi ? rv1h : pk0h,
                      hi ? pk1l : rv0l, hi ? pk1h : rv0h);
      short8 A1 = mk8(hi ? rv3l : pk2l, hi ? rv3h : pk2h,
                      hi ? pk3l : rv2l, hi ? pk3h : rv2h);
#pragma unroll
      for (int ct = 0; ct < 4; ++ct) {
        int c = ct * 32 + n32;
        short8 B0 = *(const short8*)(smem + M_OFF + c * 256 + ((rb * 4 + hi) ^ s7) * 16);
        short8 B1 = *(const short8*)(smem + M_OFF + c * 256 + ((rb * 4 + 2 + hi) ^ s7) * 16);
        acc2[ct] = __builtin_amdgcn_mfma_f32_32x32x16_bf16(A0, B0, acc2[ct], 0, 0, 0);
        acc2[ct] = __builtin_amdgcn_mfma_f32_32x32x16_bf16(A1, B1, acc2[ct], 0, 0, 0);
      }
    }

    // epilogue: h2 -> classifier partial dot (vectorized Wc/b2 reads)
#pragma unroll
    for (int ct = 0; ct < 4; ++ct) {
      int c = ct * 32 + n32;
      if (c < R_) {
        float dv = dvc[ct];
#pragma unroll
        for (int rq = 0; rq < 4; ++rq) {
          const int f0 = w * 32 + rq * 8 + hi * 4;
          f32x4 bv2 = *(const f32x4*)(b2 + f0);
          float h0 = dv * acc2[ct][rq * 4 + 0] + bv2[0]; h0 = h0 > 0.f ? h0 : 0.2f * h0;
          float h1 = dv * acc2[ct][rq * 4 + 1] + bv2[1]; h1 = h1 > 0.f ? h1 : 0.2f * h1;
          float h2 = dv * acc2[ct][rq * 4 + 2] + bv2[2]; h2 = h2 > 0.f ? h2 : 0.2f * h2;
          float h3 = dv * acc2[ct][rq * 4 + 3] + bv2[3]; h3 = h3 > 0.f ? h3 : 0.2f * h3;
          f32x4 wc0 = *(const f32x4*)(Wc + (size_t)c * H_ + f0);
          f32x4 wc1 = *(const f32x4*)(Wc + (size_t)(H_ * R_) + (size_t)c * H_ + f0);
          ps0 += h0 * wc0[0] + h1 * wc0[1] + h2 * wc0[2] + h3 * wc0[3];
          ps1 += h0 * wc1[0] + h1 * wc1[1] + h2 * wc1[2] + h3 * wc1[3];
        }
      }
    }
  }

  // ---- classifier reduction ----
#pragma unroll
  for (int off = 32; off; off >>= 1) {
    ps0 += __shfl_xor(ps0, off, 64);
    ps1 += __shfl_xor(ps1, off, 64);
  }
  float* red = (float*)(smem + RED_OFF);
  if (lane == 0) { red[w * 2] = ps0; red[w * 2 + 1] = ps1; }
  __syncthreads();
  if (tid == 0) {
    float s0 = 0.f, s1 = 0.f;
#pragma unroll
    for (int i = 0; i < 8; ++i) { s0 += red[i * 2]; s1 += red[i * 2 + 1]; }
    out[b * 2 + 0] = s0 + bc[0];
    out[b * 2 + 1] = s1 + bc[1];
  }
}

extern "C" void kernel_launch(void* const* d_in, const int* in_sizes, int n_in,
                              void* d_out, int out_size, void* d_ws, size_t ws_size,
                              hipStream_t stream) {
  const float* mM = (const float*)d_in[0];
  const float* nf = (const float*)d_in[1];
  const float* W1 = (const float*)d_in[2];
  const float* b1 = (const float*)d_in[3];
  const float* W2 = (const float*)d_in[4];
  const float* b2 = (const float*)d_in[5];
  const float* Wc = (const float*)d_in[6];
  const float* bc = (const float*)d_in[7];
  float* out = (float*)d_out;

  short* W1t = (short*)d_ws;            // 32768 bf16
  short* W2t = W1t + 32768;             // 65536 bf16

  wt_setup<<<384, 256, 0, stream>>>(W1, W2, W1t, W2t);

  hipFuncSetAttribute((const void*)gnn_fused,
                      hipFuncAttributeMaxDynamicSharedMemorySize, LDS_SIZE);
  gnn_fused<<<512, 512, LDS_SIZE, stream>>>(mM, nf, b1, b2, Wc, bc, W1t, W2t, out);
}

// Round 15
// 55.914 us; speedup vs baseline: 1.1434x; 1.1434x over previous
//
#include <hip/hip_runtime.h>

#define R_    116
#define DIN_  116
#define H_    256

typedef float  f32x4   __attribute__((ext_vector_type(4)));
typedef float  f32x16  __attribute__((ext_vector_type(16)));
typedef short  short8  __attribute__((ext_vector_type(8)));
typedef int    int4v   __attribute__((ext_vector_type(4)));
typedef int    int2v   __attribute__((ext_vector_type(2)));

// ---- LDS layout (bytes). 16B-block XOR swizzle per row (block ^= row&7).
#define M_OFF    0        // M  [128 c][128 r] bf16 pitch 256B : bb=(r>>3)^(c&7); relu(m^T)+I
#define X_OFF    32768    // X  [128 r][128 k] bf16 pitch 256B : bb=(k>>3)^(r&7); zero-padded
#define H1_OFF   65536    // H1 [128 c][256 f] bf16 pitch 512B : bb=(f>>3)^(c&7); rows>=116 zeroed
#define DINV_OFF 131072   // 128 f32 (persistent)
#define RED_OFF  131584   // 16 f32
#define LDS_SIZE 131712

#define Z16 {0.f,0.f,0.f,0.f,0.f,0.f,0.f,0.f,0.f,0.f,0.f,0.f,0.f,0.f,0.f,0.f}

__device__ __forceinline__ short f2bf(float f) {
  union { float f; unsigned u; } x; x.f = f;
  unsigned r = x.u + 0x7fffu + ((x.u >> 16) & 1u);
  return (short)(r >> 16);
}
__device__ __forceinline__ float bf2f(short s) {
  union { unsigned u; float f; } x;
  x.u = ((unsigned)(unsigned short)s) << 16;
  return x.f;
}
// HW packed f32->bf16 RTNE: identical values to f2bf, 1 instruction per pair.
__device__ __forceinline__ unsigned pack2(float lo, float hi) {
  unsigned r;
  asm("v_cvt_pk_bf16_f32 %0, %1, %2" : "=v"(r) : "v"(lo), "v"(hi));
  return r;
}
__device__ __forceinline__ short8 mk8(unsigned a, unsigned b, unsigned c, unsigned d) {
  int4v t; t[0] = (int)a; t[1] = (int)b; t[2] = (int)c; t[3] = (int)d;
  return __builtin_bit_cast(short8, t);
}

// Pre-transpose weights to bf16 Wt[f][k], zero-padded K (layer 1).
__global__ void __launch_bounds__(256) wt_setup(const float* __restrict__ W1,
                                                const float* __restrict__ W2,
                                                short* __restrict__ W1t,
                                                short* __restrict__ W2t) {
  int idx = blockIdx.x * 256 + threadIdx.x;      // 384 blocks
  if (idx < 32768) {                             // W1t [256][128]
    int f = idx >> 7, k = idx & 127;
    float v = (k < DIN_) ? W1[k * H_ + f] : 0.f;
    W1t[idx] = f2bf(v);
  } else {                                       // W2t [256][256]
    int j = idx - 32768;
    int f = j >> 8, k = j & 255;
    W2t[j] = f2bf(W2[k * H_ + f]);
  }
}

// 8 waves (512 thr), 32x32x16 MFMA. Wave w owns f-tile w*32..w*32+31 for BOTH layers.
// Phase A: D[r-quads][f=n32] = X @ W.  In-register transform (scale by dinv[r],
// pack to bf16, shfl_xor lane^32) builds phase-B A-frags xs[f=n32][r-slice]
// WITHOUT an LDS round-trip or barrier.  Phase B: D2[f-quads][c=n32] += xs @ M^T.
__global__ void __launch_bounds__(512, 2) gnn_fused(
    const float* __restrict__ mM, const float* __restrict__ nf,
    const float* __restrict__ b1, const float* __restrict__ b2,
    const float* __restrict__ Wc, const float* __restrict__ bc,
    const short* __restrict__ W1t, const short* __restrict__ W2t,
    float* __restrict__ out)
{
  extern __shared__ char smem[];
  const int b    = blockIdx.x;
  const int tid  = threadIdx.x;
  const int lane = tid & 63;
  const int w    = tid >> 6;     // 0..7 : f-tile (32 cols, both layers)
  const int n32  = lane & 31;
  const int hi   = lane >> 5;
  const int s7   = n32 & 7;

  // ---- zero M + X + H1 (128KB: covers all padding incl. H1 rows >= 116) ----
  for (int t = tid; t < 131072 / 16; t += 512)
    ((int4v*)smem)[t] = (int4v){0, 0, 0, 0};
  __syncthreads();

  // ---- fill M (transposed, relu, +1 diag) and X (bf16), coalesced f32x4 reads ----
  {
    const float* mB = mM + (size_t)b * (R_ * R_);
    const float* xB = nf + (size_t)b * (R_ * DIN_);
    for (int t4 = tid; t4 < (R_ * R_) / 4; t4 += 512) {
      f32x4 v4 = ((const f32x4*)mB)[t4];
      f32x4 x4 = ((const f32x4*)xB)[t4];
      int i0 = t4 * 4;
      int r = i0 / R_, c0 = i0 - r * R_;          // c0 % 4 == 0 (116 % 4 == 0)
#pragma unroll
      for (int e = 0; e < 4; ++e) {               // M: rows differ -> scalar stores
        int c = c0 + e;
        float v = v4[e];
        v = v > 0.f ? v : 0.f;
        if (r == c) v += 1.f;
        int ba = (r >> 3) ^ (c & 7);
        *(short*)(smem + M_OFF + c * 256 + ba * 16 + (r & 7) * 2) = f2bf(v);
      }
      {                                           // X: same row -> one 8B store
        int bx = (c0 >> 3) ^ (r & 7);
        int2v px;
        px[0] = (int)pack2(x4[0], x4[1]);
        px[1] = (int)pack2(x4[2], x4[3]);
        *(int2v*)(smem + X_OFF + r * 256 + bx * 16 + (c0 & 7) * 2) = px;
      }
    }
  }
  __syncthreads();

  // ---- deg/dinv: 4 threads per row -> persistent DINV region ----
  {
    float* dp = (float*)(smem + DINV_OFF);
    int row = tid >> 2, part = tid & 3;
    float s = 0.f;
#pragma unroll
    for (int j = 0; j < 4; ++j) {
      int bb = (part * 4 + j) ^ (row & 7);
      short8 v = *(const short8*)(smem + M_OFF + row * 256 + bb * 16);
#pragma unroll
      for (int e = 0; e < 8; ++e) s += bf2f(v[e]);
    }
    s += __shfl_xor(s, 1);
    s += __shfl_xor(s, 2);
    if (part == 0) dp[row] = (row < R_) ? rsqrtf(s) : 0.f;
  }
  __syncthreads();

  const float* dinvp = (const float*)(smem + DINV_OFF);
  float dvc[4];
#pragma unroll
  for (int ct = 0; ct < 4; ++ct) dvc[ct] = dinvp[ct * 32 + n32];

  float ps0 = 0.f, ps1 = 0.f;

  // ================= Layer 1 (no internal barriers) =================
  {
    short8 w1f[8];
#pragma unroll
    for (int ks = 0; ks < 8; ++ks)
      w1f[ks] = *(const short8*)(W1t + (size_t)(w * 32 + n32) * 128 + ks * 16 + hi * 8);

    f32x16 acc2[4];
#pragma unroll
    for (int ct = 0; ct < 4; ++ct) acc2[ct] = (f32x16)Z16;

#pragma unroll
    for (int rb = 0; rb < 4; ++rb) {
      // phase A: xw tile [32 r x 32 f], D[r-quads][f=n32]
      f32x16 acc = (f32x16)Z16;
#pragma unroll
      for (int ks = 0; ks < 8; ++ks) {
        short8 xa = *(const short8*)(smem + X_OFF + (rb * 32 + n32) * 256 +
                                     (((ks * 2 + hi) ^ s7)) * 16);
        acc = __builtin_amdgcn_mfma_f32_32x32x16_bf16(xa, w1f[ks], acc, 0, 0, 0);
      }
      // in-register: scale by dinv[r], pack bf16, exchange lane^32 -> A-frags
      f32x4 dv0 = *(const f32x4*)(dinvp + rb * 32 + 0 + hi * 4);
      f32x4 dv1 = *(const f32x4*)(dinvp + rb * 32 + 8 + hi * 4);
      f32x4 dv2 = *(const f32x4*)(dinvp + rb * 32 + 16 + hi * 4);
      f32x4 dv3 = *(const f32x4*)(dinvp + rb * 32 + 24 + hi * 4);
      unsigned pk0l = pack2(acc[0] * dv0[0],  acc[1] * dv0[1]);
      unsigned pk0h = pack2(acc[2] * dv0[2],  acc[3] * dv0[3]);
      unsigned pk1l = pack2(acc[4] * dv1[0],  acc[5] * dv1[1]);
      unsigned pk1h = pack2(acc[6] * dv1[2],  acc[7] * dv1[3]);
      unsigned pk2l = pack2(acc[8] * dv2[0],  acc[9] * dv2[1]);
      unsigned pk2h = pack2(acc[10] * dv2[2], acc[11] * dv2[3]);
      unsigned pk3l = pack2(acc[12] * dv3[0], acc[13] * dv3[1]);
      unsigned pk3h = pack2(acc[14] * dv3[2], acc[15] * dv3[3]);
      unsigned rv0l = (unsigned)__shfl_xor((int)pk0l, 32);
      unsigned rv0h = (unsigned)__shfl_xor((int)pk0h, 32);
      unsigned rv1l = (unsigned)__shfl_xor((int)pk1l, 32);
      unsigned rv1h = (unsigned)__shfl_xor((int)pk1h, 32);
      unsigned rv2l = (unsigned)__shfl_xor((int)pk2l, 32);
      unsigned rv2h = (unsigned)__shfl_xor((int)pk2h, 32);
      unsigned rv3l = (unsigned)__shfl_xor((int)pk3l, 32);
      unsigned rv3h = (unsigned)__shfl_xor((int)pk3h, 32);
      short8 A0 = mk8(hi ? rv1l : pk0l, hi ? rv1h : pk0h,
                      hi ? pk1l : rv0l, hi ? pk1h : rv0h);
      short8 A1 = mk8(hi ? rv3l : pk2l, hi ? rv3h : pk2h,
                      hi ? pk3l : rv2l, hi ? pk3h : rv2h);
      // phase B: D2[f-quads][c=n32] += xs @ M^T (K = this rb's 32 r)
#pragma unroll
      for (int ct = 0; ct < 4; ++ct) {
        int c = ct * 32 + n32;
        short8 B0 = *(const short8*)(smem + M_OFF + c * 256 + ((rb * 4 + hi) ^ s7) * 16);
        short8 B1 = *(const short8*)(smem + M_OFF + c * 256 + ((rb * 4 + 2 + hi) ^ s7) * 16);
        acc2[ct] = __builtin_amdgcn_mfma_f32_32x32x16_bf16(A0, B0, acc2[ct], 0, 0, 0);
        acc2[ct] = __builtin_amdgcn_mfma_f32_32x32x16_bf16(A1, B1, acc2[ct], 0, 0, 0);
      }
    }

    // epilogue: h1 = leaky(dinv[c]*agg + b1[f]) -> H1[c][f]
    f32x4 bv[4];
#pragma unroll
    for (int rq = 0; rq < 4; ++rq)
      bv[rq] = *(const f32x4*)(b1 + w * 32 + rq * 8 + hi * 4);
#pragma unroll
    for (int ct = 0; ct < 4; ++ct) {
      int c = ct * 32 + n32;
      if (c < R_) {
        float dv = dvc[ct];
#pragma unroll
        for (int rq = 0; rq < 4; ++rq) {
          const int f0 = w * 32 + rq * 8 + hi * 4;
          float h0 = dv * acc2[ct][rq * 4 + 0] + bv[rq][0]; h0 = h0 > 0.f ? h0 : 0.2f * h0;
          float h1 = dv * acc2[ct][rq * 4 + 1] + bv[rq][1]; h1 = h1 > 0.f ? h1 : 0.2f * h1;
          float h2 = dv * acc2[ct][rq * 4 + 2] + bv[rq][2]; h2 = h2 > 0.f ? h2 : 0.2f * h2;
          float h3 = dv * acc2[ct][rq * 4 + 3] + bv[rq][3]; h3 = h3 > 0.f ? h3 : 0.2f * h3;
          int bb = (w * 4 + rq) ^ s7;            // (f0>>3)^(c&7), c&7==s7
          int2v pk;
          pk[0] = (int)pack2(h0, h1);
          pk[1] = (int)pack2(h2, h3);
          *(int2v*)(smem + H1_OFF + c * 512 + bb * 16 + hi * 8) = pk;
        }
      }
    }
  }
  __syncthreads();   // H1 complete

  // ================= Layer 2 (no internal barriers) =================
  {
    f32x16 acc2[4];
#pragma unroll
    for (int ct = 0; ct < 4; ++ct) acc2[ct] = (f32x16)Z16;

#pragma unroll
    for (int rb = 0; rb < 4; ++rb) {
      f32x16 acc = (f32x16)Z16;
#pragma unroll
      for (int ks = 0; ks < 16; ++ks) {
        short8 ha = *(const short8*)(smem + H1_OFF + (rb * 32 + n32) * 512 +
                                     (((ks * 2 + hi) ^ s7)) * 16);
        short8 wfr = *(const short8*)(W2t + (size_t)(w * 32 + n32) * 256 + ks * 16 + hi * 8);
        acc = __builtin_amdgcn_mfma_f32_32x32x16_bf16(ha, wfr, acc, 0, 0, 0);
      }
      f32x4 dv0 = *(const f32x4*)(dinvp + rb * 32 + 0 + hi * 4);
      f32x4 dv1 = *(const f32x4*)(dinvp + rb * 32 + 8 + hi * 4);
      f32x4 dv2 = *(const f32x4*)(dinvp + rb * 32 + 16 + hi * 4);
      f32x4 dv3 = *(const f32x4*)(dinvp + rb * 32 + 24 + hi * 4);
      unsigned pk0l = pack2(acc[0] * dv0[0],  acc[1] * dv0[1]);
      unsigned pk0h = pack2(acc[2] * dv0[2],  acc[3] * dv0[3]);
      unsigned pk1l = pack2(acc[4] * dv1[0],  acc[5] * dv1[1]);
      unsigned pk1h = pack2(acc[6] * dv1[2],  acc[7] * dv1[3]);
      unsigned pk2l = pack2(acc[8] * dv2[0],  acc[9] * dv2[1]);
      unsigned pk2h = pack2(acc[10] * dv2[2], acc[11] * dv2[3]);
      unsigned pk3l = pack2(acc[12] * dv3[0], acc[13] * dv3[1]);
      unsigned pk3h = pack2(acc[14] * dv3[2], acc[15] * dv3[3]);
      unsigned rv0l = (unsigned)__shfl_xor((int)pk0l, 32);
      unsigned rv0h = (unsigned)__shfl_xor((int)pk0h, 32);
      unsigned rv1l = (unsigned)__shfl_xor((int)pk1l, 32);
      unsigned rv1h = (unsigned)__shfl_xor((int)pk1h, 32);
      unsigned rv2l = (unsigned)__shfl_xor((int)pk2l, 32);
      unsigned rv2h = (unsigned)__shfl_xor((int)pk2h, 32);
      unsigned rv3l = (unsigned)__shfl_xor((int)pk3l, 32);
      unsigned rv3h = (unsigned)__shfl_xor((int)pk3h, 32);
      short8 A0 = mk8(hi ? rv1l : pk0l, hi ? rv1h : pk0h,
                      hi ? pk1l : rv0l, hi ? pk1h : rv0h);
      short8 A1 = mk8(hi ? rv3l : pk2l, hi ? rv3h : pk2h,
                      hi ? pk3l : rv2l, hi ? pk3h : rv2h);
#pragma unroll
      for (int ct = 0; ct < 4; ++ct) {
        int c = ct * 32 + n32;
        short8 B0 = *(const short8*)(smem + M_OFF + c * 256 + ((rb * 4 + hi) ^ s7) * 16);
        short8 B1 = *(const short8*)(smem + M_OFF + c * 256 + ((rb * 4 + 2 + hi) ^ s7) * 16);
        acc2[ct] = __builtin_amdgcn_mfma_f32_32x32x16_bf16(A0, B0, acc2[ct], 0, 0, 0);
        acc2[ct] = __builtin_amdgcn_mfma_f32_32x32x16_bf16(A1, B1, acc2[ct], 0, 0, 0);
      }
    }

    // epilogue: h2 -> classifier partial dot (vectorized Wc/b2 reads)
#pragma unroll
    for (int ct = 0; ct < 4; ++ct) {
      int c = ct * 32 + n32;
      if (c < R_) {
        float dv = dvc[ct];
#pragma unroll
        for (int rq = 0; rq < 4; ++rq) {
          const int f0 = w * 32 + rq * 8 + hi * 4;
          f32x4 bv2 = *(const f32x4*)(b2 + f0);
          float h0 = dv * acc2[ct][rq * 4 + 0] + bv2[0]; h0 = h0 > 0.f ? h0 : 0.2f * h0;
          float h1 = dv * acc2[ct][rq * 4 + 1] + bv2[1]; h1 = h1 > 0.f ? h1 : 0.2f * h1;
          float h2 = dv * acc2[ct][rq * 4 + 2] + bv2[2]; h2 = h2 > 0.f ? h2 : 0.2f * h2;
          float h3 = dv * acc2[ct][rq * 4 + 3] + bv2[3]; h3 = h3 > 0.f ? h3 : 0.2f * h3;
          f32x4 wc0 = *(const f32x4*)(Wc + (size_t)c * H_ + f0);
          f32x4 wc1 = *(const f32x4*)(Wc + (size_t)(H_ * R_) + (size_t)c * H_ + f0);
          ps0 += h0 * wc0[0] + h1 * wc0[1] + h2 * wc0[2] + h3 * wc0[3];
          ps1 += h0 * wc1[0] + h1 * wc1[1] + h2 * wc1[2] + h3 * wc1[3];
        }
      }
    }
  }

  // ---- classifier reduction ----
#pragma unroll
  for (int off = 32; off; off >>= 1) {
    ps0 += __shfl_xor(ps0, off, 64);
    ps1 += __shfl_xor(ps1, off, 64);
  }
  float* red = (float*)(smem + RED_OFF);
  if (lane == 0) { red[w * 2] = ps0; red[w * 2 + 1] = ps1; }
  __syncthreads();
  if (tid == 0) {
    float s0 = 0.f, s1 = 0.f;
#pragma unroll
    for (int i = 0; i < 8; ++i) { s0 += red[i * 2]; s1 += red[i * 2 + 1]; }
    out[b * 2 + 0] = s0 + bc[0];
    out[b * 2 + 1] = s1 + bc[1];
  }
}

extern "C" void kernel_launch(void* const* d_in, const int* in_sizes, int n_in,
                              void* d_out, int out_size, void* d_ws, size_t ws_size,
                              hipStream_t stream) {
  const float* mM = (const float*)d_in[0];
  const float* nf = (const float*)d_in[1];
  const float* W1 = (const float*)d_in[2];
  const float* b1 = (const float*)d_in[3];
  const float* W2 = (const float*)d_in[4];
  const float* b2 = (const float*)d_in[5];
  const float* Wc = (const float*)d_in[6];
  const float* bc = (const float*)d_in[7];
  float* out = (float*)d_out;

  short* W1t = (short*)d_ws;            // 32768 bf16
  short* W2t = W1t + 32768;             // 65536 bf16

  wt_setup<<<384, 256, 0, stream>>>(W1, W2, W1t, W2t);

  hipFuncSetAttribute((const void*)gnn_fused,
                      hipFuncAttributeMaxDynamicSharedMemorySize, LDS_SIZE);
  gnn_fused<<<512, 512, LDS_SIZE, stream>>>(mM, nf, b1, b2, Wc, bc, W1t, W2t, out);
}